// Round 18
// baseline (57.537 us; speedup 1.0000x reference)
//
#include <hip/hip_runtime.h>

#define NB   8192
#define NT   2048
#define OBS  30
#define CCH  32               // 64-long chunks per row
#define RPB  16               // rows per block (4 per wave, 2 tiles of 2)
#define NTHR 256              // 4 waves
#define CSTR 68               // chunk record stride (17 float4)

typedef float v2f __attribute__((ext_vector_type(2)));

// Packed two-step on a 32-slot ring: advances steps t=j, j+1 (j even,
// compile-time). wxp[m] = (wx[m], wx[m-1]), wx[-1]=0; w29 = wx[29].
__device__ __forceinline__ v2f step2(float (&r)[32], const v2f (&wxp)[OBS],
                                     float w29, int j, float uw0, float uw1) {
  v2f a0 = {uw0, uw1};
  v2f a1 = {0.f, 0.f};
  v2f a2 = {0.f, 0.f};
  #pragma unroll
  for (int m = 0; m < OBS; m += 3) {
    float r0 = r[(j + m) & 31], r1 = r[(j + m + 1) & 31], r2 = r[(j + m + 2) & 31];
    a0 = __builtin_elementwise_fma(wxp[m],     (v2f){r0, r0}, a0);
    a1 = __builtin_elementwise_fma(wxp[m + 1], (v2f){r1, r1}, a1);
    a2 = __builtin_elementwise_fma(wxp[m + 2], (v2f){r2, r2}, a2);
  }
  v2f A = (a0 + a1) + a2;
  float o0 = A.x;
  float o1 = fmaf(w29, o0, A.y);
  r[(j + 30) & 31] = o0;
  r[(j + 31) & 31] = o1;
  return (v2f){o0, o1};
}

// 15-pair packed dot: taps 0..29 against sv pairs, horizontal-reduced, + p.
__device__ __forceinline__ float dot15(const v2f (&cp)[15], const v2f (&sv)[16],
                                       float p) {
  v2f a0 = cp[0] * sv[0];
  v2f a1 = cp[1] * sv[1];
  v2f a2 = cp[2] * sv[2];
  #pragma unroll
  for (int m = 3; m < 15; m += 3) {
    a0 = __builtin_elementwise_fma(cp[m],     sv[m],     a0);
    a1 = __builtin_elementwise_fma(cp[m + 1], sv[m + 1], a1);
    a2 = __builtin_elementwise_fma(cp[m + 2], sv[m + 2], a2);
  }
  v2f A = (a0 + a1) + a2;
  return (A.x + A.y) + p;
}

// Fully fused, wave-decoupled, packed-FMA, C by wave 0 only, and a 2-tile
// per-wave software pipeline: tile-1 global loads are issued before tile-0's
// serial scan so HBM drains under DS/VALU work instead of stalling everyone.
__global__ void __launch_bounds__(NTHR, 2)
k_fused(const float* __restrict__ u, const float* __restrict__ x0,
        const float* __restrict__ Wx, const float* __restrict__ Wf,
        float* __restrict__ out) {
  __shared__ float tile[4 * 2 * CCH * CSTR];  // 69.6 KB: per-wave 64 records
  __shared__ float Cb[64 * 33];               // 8.4 KB: C[t][i], stride 33
  __shared__ float sbuf[RPB * 32];            // per-row running state slot
  const int tid  = threadIdx.x;
  const int wv   = tid >> 6;
  const int lane = tid & 63;
  const int half = lane >> 5;
  const int k    = lane & 31;
  const int row0 = blockIdx.x * RPB;
  const int wr0  = row0 + 4 * wv;             // this wave's first row

  v2f wxp[OBS];
  wxp[0] = (v2f){Wx[0], 0.f};
  #pragma unroll
  for (int m = 1; m < OBS; ++m) wxp[m] = (v2f){Wx[m], Wx[m - 1]};
  const float w29 = wxp[29].x;
  const float wf  = Wf[0];
  // x0 for both tiles' rows (row = wr0 + 2*tl + half)
  const float x0v0 = (k < OBS) ? x0[(size_t)(wr0 + half) * OBS + k] : 0.f;
  const float x0v1 = (k < OBS) ? x0[(size_t)(wr0 + 2 + half) * OBS + k] : 0.f;
  sbuf[(4 * wv + half) * 32 + k]     = x0v0;
  sbuf[(4 * wv + 2 + half) * 32 + k] = x0v1;

  // ---- tile-0 u loads (2 rows)
  float4 stg[16];
  const float* ubw = u + (size_t)wr0 * NT;
  #pragma unroll
  for (int i = 0; i < 16; ++i) {
    int v = i * 64 + lane, rr = v >> 9, p = v & 511;
    stg[i] = *(const float4*)(ubw + (size_t)rr * NT + 4 * p);
  }

  // ---- C[t][i] (t<64, i<30): wave 0 only; published via the one barrier.
  if (wv == 0) {
    float r[32];
    #pragma unroll
    for (int i = 0; i < 32; ++i) r[i] = (k < OBS && i == k) ? 1.f : 0.f;
    #pragma unroll
    for (int s = 0; s < 32; ++s) {
      v2f o = step2(r, wxp, w29, (2 * s) & 31, 0.f, 0.f);
      if (lane < OBS) {
        Cb[(2 * s) * 33 + lane]     = o.x;
        Cb[(2 * s + 1) * 33 + lane] = o.y;
      }
    }
  }

  // ---- stage tile 0 into this wave's private region
  float* sub = &tile[(wv * 2 * CCH) * CSTR];
  #pragma unroll
  for (int i = 0; i < 16; ++i) {
    int v = i * 64 + lane, rr = v >> 9, p = v & 511;
    int c = p >> 4, q = p & 15;
    *(float4*)(&sub[(rr * CCH + c) * CSTR + 4 * q]) = stg[i];
  }
  __syncthreads();                            // publish Cb (only block sync)

  // ---- my two C rows (t = 2k, 2k+1) as packed pairs
  v2f c0p[15], c1p[15];
  #pragma unroll
  for (int m = 0; m < 15; ++m)
    c0p[m] = (v2f){Cb[(2 * k) * 33 + 2 * m], Cb[(2 * k) * 33 + 2 * m + 1]};
  #pragma unroll
  for (int m = 0; m < 15; ++m)
    c1p[m] = (v2f){Cb[(2 * k + 1) * 33 + 2 * m],
                   Cb[(2 * k + 1) * 33 + 2 * m + 1]};

  #pragma unroll 1
  for (int tl = 0; tl < 2; ++tl) {
    // ---- phase 2: zero-init particular recurrence; lane <-> chunk
    {
      float r[32];
      #pragma unroll
      for (int i = 0; i < 32; ++i) r[i] = 0.f;
      float* tc = &sub[lane * CSTR];
      #pragma unroll
      for (int q = 0; q < 16; ++q) {
        float4 u4 = *(const float4*)(tc + 4 * q);
        v2f oA = step2(r, wxp, w29, (4 * q)     & 31, wf * u4.x, wf * u4.y);
        v2f oB = step2(r, wxp, w29, (4 * q + 2) & 31, wf * u4.z, wf * u4.w);
        *(float4*)(tc + 4 * q) = make_float4(oA.x, oA.y, oB.x, oB.y);
      }
    }
    // ---- issue tile-1 u loads now: they drain under tile-0's serial scan
    if (tl == 0) {
      const float* ub1 = ubw + 2 * (size_t)NT;
      #pragma unroll
      for (int i = 0; i < 16; ++i) {
        int v = i * 64 + lane, rr = v >> 9, p = v & 511;
        stg[i] = *(const float4*)(ub1 + (size_t)rr * NT + 4 * p);
      }
    }
    __builtin_amdgcn_wave_barrier();          // order p2 DS writes vs p3 reads

    // ---- phase 3: serial chunk scan + correction for this tile's 2 rows
    const int lr = 4 * wv + 2 * tl + half;
    float* sl = &sbuf[lr * 32];
    const float* trow = &sub[half * CCH * CSTR];
    float* orow = out + (size_t)(row0 + lr) * NT;
    float2 pq = *(const float2*)(&trow[2 * k]);
    #pragma unroll 1
    for (int c = 0; c < CCH; ++c) {
      v2f sv2[16];
      #pragma unroll
      for (int q = 0; q < 8; ++q) {
        float4 v = *(const float4*)(sl + 4 * q);
        sv2[2 * q]     = (v2f){v.x, v.y};
        sv2[2 * q + 1] = (v2f){v.z, v.w};
      }
      int cn = (c + 1 < CCH) ? c + 1 : c;
      float2 pqn = *(const float2*)(&trow[cn * CSTR + 2 * k]);
      float t0 = dot15(c0p, sv2, pq.x);       // true out, t = c*64 + 2k
      float t1 = dot15(c1p, sv2, pq.y);       // true out, t = c*64 + 2k+1
      if (k >= 17)                            // s_next[i] = out[34+i]
        *(float2*)(&sl[2 * k - 34]) = make_float2(t0, t1);
      *(float2*)(&orow[c * 64 + 2 * k]) = make_float2(t0, t1);
      pq = pqn;
      __builtin_amdgcn_wave_barrier();        // fence slot write vs next reads
    }
    __builtin_amdgcn_wave_barrier();          // p3 reads done before restage

    // ---- stage tile 1 (vmcnt waits here, mostly already drained)
    if (tl == 0) {
      #pragma unroll
      for (int i = 0; i < 16; ++i) {
        int v = i * 64 + lane, rr = v >> 9, p = v & 511;
        int c = p >> 4, q = p & 15;
        *(float4*)(&sub[(rr * CCH + c) * CSTR + 4 * q]) = stg[i];
      }
      __builtin_amdgcn_wave_barrier();        // staging vs next p2 reads
    }
  }
}

extern "C" void kernel_launch(void* const* d_in, const int* in_sizes, int n_in,
                              void* d_out, int out_size, void* d_ws, size_t ws_size,
                              hipStream_t stream) {
  const float* u  = (const float*)d_in[0];
  const float* x0 = (const float*)d_in[1];
  const float* Wx = (const float*)d_in[2];
  const float* Wf = (const float*)d_in[3];
  float* out = (float*)d_out;

  hipLaunchKernelGGL(k_fused, dim3(NB / RPB), dim3(NTHR), 0, stream,
                     u, x0, Wx, Wf, out);
}

// Round 19
// 43.971 us; speedup vs baseline: 1.3085x; 1.3085x over previous
//
#include <hip/hip_runtime.h>

#define NB   8192
#define NT   2048
#define OBS  30
#define CCH  32               // 64-long chunks per row
#define RPB  8                // rows per block
#define NTHR 256              // 4 waves; wave wv owns rows 2wv, 2wv+1 end-to-end
#define CSTR 68               // chunk record stride (17 float4)

typedef float v2f __attribute__((ext_vector_type(2)));

// Packed two-step on a 32-slot ring: advances steps t=j, j+1 (j even,
// compile-time). wxp[m] = (wx[m], wx[m-1]), wx[-1]=0; w29 = wx[29].
// x-lane accumulates out_j, y-lane out_{j+1} minus its out_j-feedback tap
// (both share multiplicand r[j+m] -> one v_pk_fma_f32 per tap).
__device__ __forceinline__ v2f step2(float (&r)[32], const v2f (&wxp)[OBS],
                                     float w29, int j, float uw0, float uw1) {
  v2f a0 = {uw0, uw1};
  v2f a1 = {0.f, 0.f};
  v2f a2 = {0.f, 0.f};
  #pragma unroll
  for (int m = 0; m < OBS; m += 3) {
    float r0 = r[(j + m) & 31], r1 = r[(j + m + 1) & 31], r2 = r[(j + m + 2) & 31];
    a0 = __builtin_elementwise_fma(wxp[m],     (v2f){r0, r0}, a0);
    a1 = __builtin_elementwise_fma(wxp[m + 1], (v2f){r1, r1}, a1);
    a2 = __builtin_elementwise_fma(wxp[m + 2], (v2f){r2, r2}, a2);
  }
  v2f A = (a0 + a1) + a2;
  float o0 = A.x;                     // out_j
  float o1 = fmaf(w29, o0, A.y);      // out_{j+1} = A.y + wx[29]*out_j
  r[(j + 30) & 31] = o0;
  r[(j + 31) & 31] = o1;
  return (v2f){o0, o1};
}

// 15-pair packed dot: taps 0..29 against sv pairs, horizontal-reduced, + p.
__device__ __forceinline__ float dot15(const v2f (&cp)[15], const v2f (&sv)[16],
                                       float p) {
  v2f a0 = cp[0] * sv[0];
  v2f a1 = cp[1] * sv[1];
  v2f a2 = cp[2] * sv[2];
  #pragma unroll
  for (int m = 3; m < 15; m += 3) {
    a0 = __builtin_elementwise_fma(cp[m],     sv[m],     a0);
    a1 = __builtin_elementwise_fma(cp[m + 1], sv[m + 1], a1);
    a2 = __builtin_elementwise_fma(cp[m + 2], sv[m + 2], a2);
  }
  v2f A = (a0 + a1) + a2;
  return (A.x + A.y) + p;
}

// Fully fused, wave-decoupled, packed-FMA. C computed by wave 0 only.
__global__ void __launch_bounds__(NTHR, 2)
k_fused(const float* __restrict__ u, const float* __restrict__ x0,
        const float* __restrict__ Wx, const float* __restrict__ Wf,
        float* __restrict__ out) {
  __shared__ float tile[RPB * CCH * CSTR];  // 69.6 KB: [row*32+chunk][68]
  __shared__ float Cb[64 * 33];             // 8.4 KB: C[t][i], stride 33
  __shared__ float sbuf[RPB * 32];          // per-row running state slot
  const int tid  = threadIdx.x;
  const int wv   = tid >> 6;
  const int lane = tid & 63;
  const int half = lane >> 5;
  const int k    = lane & 31;
  const int row0 = blockIdx.x * RPB;
  const int lr   = wv * 2 + half;           // phase-3 local row
  const int row  = row0 + lr;

  // taps as packed pairs (wx[m], wx[m-1]); w29 kept scalar for the feedback
  v2f wxp[OBS];
  wxp[0] = (v2f){Wx[0], 0.f};
  #pragma unroll
  for (int m = 1; m < OBS; ++m) wxp[m] = (v2f){Wx[m], Wx[m - 1]};
  const float w29 = wxp[29].x;
  const float wf  = Wf[0];
  const float x0v = (k < OBS) ? x0[(size_t)row * OBS + k] : 0.f;

  // ---- wave-local u loads: this wave's 2 rows (land while C is computed)
  float4 stg[16];
  const float* ub = u + ((size_t)row0 + 2 * wv) * NT;
  #pragma unroll
  for (int i = 0; i < 16; ++i) {
    int v = i * 64 + lane, rr = v >> 9, p = v & 511;
    stg[i] = *(const float4*)(ub + (size_t)rr * NT + 4 * p);
  }

  // ---- C[t][i] (t<64, i<30): homogeneous out at step t from unit state e_i.
  // WAVE 0 ONLY (lane = column; lanes 32..63 idle-duplicate). Other waves
  // proceed straight to staging; the barrier below publishes Cb to them.
  if (wv == 0) {
    float r[32];
    #pragma unroll
    for (int i = 0; i < 32; ++i) r[i] = (k < OBS && i == k) ? 1.f : 0.f;
    #pragma unroll
    for (int s = 0; s < 32; ++s) {
      v2f o = step2(r, wxp, w29, (2 * s) & 31, 0.f, 0.f);
      if (lane < OBS) {
        Cb[(2 * s) * 33 + lane]     = o.x;
        Cb[(2 * s + 1) * 33 + lane] = o.y;
      }
    }
  }
  // x0 -> this wave's two state slots (zeros in 30,31: read-but-unused pair)
  sbuf[lr * 32 + k] = x0v;

  // ---- wave-local staging: chunk-major into this wave's 64 records
  float* sub = &tile[(wv * 2 * CCH) * CSTR];
  #pragma unroll
  for (int i = 0; i < 16; ++i) {
    int v = i * 64 + lane, rr = v >> 9, p = v & 511;
    int c = p >> 4, q = p & 15;
    *(float4*)(&sub[(rr * CCH + c) * CSTR + 4 * q]) = stg[i];
  }
  __syncthreads();                          // publish Cb (only block-wide sync)

  // ---- my two C rows (t = 2k, 2k+1) as 15 packed pairs each
  v2f c0p[15], c1p[15];
  #pragma unroll
  for (int m = 0; m < 15; ++m)
    c0p[m] = (v2f){Cb[(2 * k) * 33 + 2 * m], Cb[(2 * k) * 33 + 2 * m + 1]};
  #pragma unroll
  for (int m = 0; m < 15; ++m)
    c1p[m] = (v2f){Cb[(2 * k + 1) * 33 + 2 * m],
                   Cb[(2 * k + 1) * 33 + 2 * m + 1]};

  // ---- phase 2 (wave-local): zero-init particular recurrence; lane <-> chunk
  {
    float r[32];
    #pragma unroll
    for (int i = 0; i < 32; ++i) r[i] = 0.f;
    float* tc = &sub[lane * CSTR];
    #pragma unroll
    for (int q = 0; q < 16; ++q) {
      float4 u4 = *(const float4*)(tc + 4 * q);
      v2f oA = step2(r, wxp, w29, (4 * q)     & 31, wf * u4.x, wf * u4.y);
      v2f oB = step2(r, wxp, w29, (4 * q + 2) & 31, wf * u4.z, wf * u4.w);
      *(float4*)(tc + 4 * q) = make_float4(oA.x, oA.y, oB.x, oB.y);
    }
  }
  __builtin_amdgcn_wave_barrier();          // order p2 DS writes vs p3 reads

  // ---- phase 3 (wave-local): serial chunk scan + correction for 2 rows
  float* sl = &sbuf[lr * 32];
  const float* trow = &sub[half * CCH * CSTR];
  float* orow = out + (size_t)row * NT;
  float2 pq = *(const float2*)(&trow[2 * k]);   // prefetch chunk 0 particular
  #pragma unroll 1
  for (int c = 0; c < CCH; ++c) {
    v2f sv2[16];
    #pragma unroll
    for (int q = 0; q < 8; ++q) {           // broadcast b128 (one slot/group)
      float4 v = *(const float4*)(sl + 4 * q);
      sv2[2 * q]     = (v2f){v.x, v.y};
      sv2[2 * q + 1] = (v2f){v.z, v.w};
    }
    int cn = (c + 1 < CCH) ? c + 1 : c;     // branchless prefetch index
    float2 pqn = *(const float2*)(&trow[cn * CSTR + 2 * k]);  // off serial path
    float t0 = dot15(c0p, sv2, pq.x);       // true out, t = c*64 + 2k
    float t1 = dot15(c1p, sv2, pq.y);       // true out, t = c*64 + 2k+1
    if (k >= 17)                            // s_next[i] = out[34+i]
      *(float2*)(&sl[2 * k - 34]) = make_float2(t0, t1);
    *(float2*)(&orow[c * 64 + 2 * k]) = make_float2(t0, t1);  // 256B/group
    pq = pqn;
    __builtin_amdgcn_wave_barrier();        // fence slot write vs next reads
  }
}

extern "C" void kernel_launch(void* const* d_in, const int* in_sizes, int n_in,
                              void* d_out, int out_size, void* d_ws, size_t ws_size,
                              hipStream_t stream) {
  const float* u  = (const float*)d_in[0];
  const float* x0 = (const float*)d_in[1];
  const float* Wx = (const float*)d_in[2];
  const float* Wf = (const float*)d_in[3];
  float* out = (float*)d_out;

  hipLaunchKernelGGL(k_fused, dim3(NB / RPB), dim3(NTHR), 0, stream,
                     u, x0, Wx, Wf, out);
}